// Round 3
// baseline (339.802 us; speedup 1.0000x reference)
//
#include <hip/hip_runtime.h>

// VQ-VAE vector quantizer, fp32, MI355X — round 3: LDS-staged codebook chunks.
// N=131072 rows, D=64, K=1024. d_out = quantized[8388608] + loss[1] + indices[131072].
// Block = 256 threads / 64 rows (lane=row). Codebook streamed through LDS in
// 16 chunks of 64 codes (16 KB); all 4 waves scan the shared chunk, wave w
// owning codes [w*16, w*16+16) of it. Distances bit-identical to rounds 1/2:
//   d = fl(fl(sx + se[j]) - fl(2*dot)), sequential-FMA dot over d.
// Argmin: within-wave ascending strict < ; cross-wave combine breaks distance
// ties by smaller index == global first-index argmin (reference semantics).

constexpr int Dm = 64;
constexpr int Kn = 1024;
constexpr long NR = 131072;
constexpr long QE = NR * (long)Dm;   // 8388608
constexpr int RB = 64;               // rows per block
constexpr int NBLK = (int)(NR / RB); // 2048
constexpr int CH = 64;               // codes per staged chunk (16 KB)
constexpr int NCH = Kn / CH;         // 16 chunks

__global__ __launch_bounds__(256) void vq_norms(const float* __restrict__ cb,
                                                float* __restrict__ se)
{
    int j = blockIdx.x * 256 + threadIdx.x;   // 4 blocks x 256 = 1024
    const float* e = cb + (size_t)j * Dm;
    float s = 0.f;
    #pragma unroll
    for (int d = 0; d < Dm; ++d) s = fmaf(e[d], e[d], s);  // same bits as r1/r2
    se[j] = s;
}

__global__ __launch_bounds__(256, 4) void vq_main(const float* __restrict__ inp,
                                                  const float* __restrict__ cb,
                                                  const float* __restrict__ seg,
                                                  float* __restrict__ out,
                                                  double* __restrict__ part)
{
    __shared__ float cbuf[CH * Dm];   // 16 KB staged chunk
    __shared__ float se[Kn];          // 4 KB codebook norms
    __shared__ float bd[4][RB];
    __shared__ int   bi[4][RB];
    __shared__ int   comb[RB];
    __shared__ double red[256];

    const int tid = threadIdx.x;
    const int w = tid >> 6;           // wave id
    const int l = tid & 63;           // lane = row-in-block

    #pragma unroll
    for (int k = 0; k < 4; ++k) se[tid + 256 * k] = seg[tid + 256 * k];

    const long row = (long)blockIdx.x * RB + l;
    const float* xr = inp + row * (long)Dm;
    float x[Dm];
    #pragma unroll
    for (int d0 = 0; d0 < Dm; d0 += 4) {
        float4 v = *reinterpret_cast<const float4*>(xr + d0);
        x[d0] = v.x; x[d0 + 1] = v.y; x[d0 + 2] = v.z; x[d0 + 3] = v.w;
    }
    float sx = 0.f;
    #pragma unroll
    for (int d = 0; d < Dm; ++d) sx = fmaf(x[d], x[d], sx);

    float best = __builtin_inff();
    int bidx = 0;
    const float4* gcb = reinterpret_cast<const float4*>(cb);

    for (int ch = 0; ch < NCH; ++ch) {
        __syncthreads();   // all waves done reading previous chunk
        {   // stage chunk ch: 1024 float4s, coalesced, conflict-free ds_write
            const float4* src = gcb + (size_t)ch * (CH * Dm / 4);
            float4* dst = reinterpret_cast<float4*>(cbuf);
            #pragma unroll
            for (int r = 0; r < 4; ++r) dst[r * 256 + tid] = src[r * 256 + tid];
        }
        __syncthreads();   // chunk visible to all waves

        const int jb = ch * CH + w * 16;                 // this wave's code range
        const float* ebase = cbuf + (w * 16) * Dm;
        #pragma unroll 2
        for (int c = 0; c < 16; ++c) {
            const float4* ep = reinterpret_cast<const float4*>(ebase + c * Dm);
            float a = 0.f;
            #pragma unroll
            for (int d4 = 0; d4 < 16; ++d4) {            // 16x ds_read_b128 broadcast
                float4 ev = ep[d4];
                a = fmaf(x[4 * d4 + 0], ev.x, a);
                a = fmaf(x[4 * d4 + 1], ev.y, a);
                a = fmaf(x[4 * d4 + 2], ev.z, a);
                a = fmaf(x[4 * d4 + 3], ev.w, a);
            }
            float dist = (sx + se[jb + c]) - 2.0f * a;   // exact r1/r2 formula
            if (dist < best) { best = dist; bidx = jb + c; }  // strict <
        }
    }

    bd[w][l] = best;
    bi[w][l] = bidx;
    __syncthreads();

    // cross-wave combine: min distance, tie -> smaller index (== first-index scan)
    if (w == 0) {
        float b = bd[0][l]; int ii = bi[0][l];
        #pragma unroll
        for (int q = 1; q < 4; ++q) {
            float d = bd[q][l]; int iq = bi[q][l];
            if (d < b || (d == b && iq < ii)) { b = d; ii = iq; }
        }
        comb[l] = ii;
        out[QE + 1 + row] = (float)ii;
    }
    __syncthreads();

    // quantized write, redistributed: thread -> (row tid>>2, dim quarter tid&3)
    const int r2 = tid >> 2;
    const int dq = (tid & 3) * 16;
    const long grow = (long)blockIdx.x * RB + r2;
    const float* xr2 = inp + grow * (long)Dm + dq;
    const float* q2  = cb + (size_t)comb[r2] * Dm + dq;
    float* outq = out + grow * (long)Dm + dq;
    double s = 0.0;
    #pragma unroll
    for (int d0 = 0; d0 < 16; d0 += 4) {
        float4 xv = *reinterpret_cast<const float4*>(xr2 + d0);
        float4 qv = *reinterpret_cast<const float4*>(q2 + d0);
        float4 ov;
        float m0 = qv.x - xv.x; ov.x = xv.x + m0;   // replicate x + (q - x)
        float m1 = qv.y - xv.y; ov.y = xv.y + m1;
        float m2 = qv.z - xv.z; ov.z = xv.z + m2;
        float m3 = qv.w - xv.w; ov.w = xv.w + m3;
        s += (double)m0 * m0 + (double)m1 * m1 + (double)m2 * m2 + (double)m3 * m3;
        *reinterpret_cast<float4*>(outq + d0) = ov;
    }

    red[tid] = s;
    __syncthreads();
    for (int k = 128; k > 0; k >>= 1) {
        if (tid < k) red[tid] += red[tid + k];
        __syncthreads();
    }
    if (tid == 0) part[blockIdx.x] = red[0];
}

__global__ __launch_bounds__(256) void vq_fin(const double* __restrict__ part,
                                              float* __restrict__ out)
{
    __shared__ double red[256];
    const int tid = threadIdx.x;
    double s = 0.0;
    #pragma unroll
    for (int k = 0; k < 8; ++k) s += part[tid + 256 * k];   // fixed order
    red[tid] = s;
    __syncthreads();
    for (int k = 128; k > 0; k >>= 1) {
        if (tid < k) red[tid] += red[tid + k];
        __syncthreads();
    }
    if (tid == 0) {
        float m = (float)(red[0] / (double)QE);   // mean((q-x)^2)
        out[QE] = m + 0.25f * m;                  // q_loss + 0.25 * e_loss
    }
}

extern "C" void kernel_launch(void* const* d_in, const int* in_sizes, int n_in,
                              void* d_out, int out_size, void* d_ws, size_t ws_size,
                              hipStream_t stream)
{
    const float* inp = (const float*)d_in[0];
    const float* cb  = (const float*)d_in[1];
    float* out = (float*)d_out;
    float* se    = (float*)d_ws;                    // 4 KB
    double* part = (double*)((char*)d_ws + 4096);   // 16 KB

    vq_norms<<<4, 256, 0, stream>>>(cb, se);
    vq_main<<<NBLK, 256, 0, stream>>>(inp, cb, se, out, part);
    vq_fin<<<1, 256, 0, stream>>>(part, out);
}

// Round 4
// 300.893 us; speedup vs baseline: 1.1293x; 1.1293x over previous
//
#include <hip/hip_runtime.h>

// VQ-VAE vector quantizer, fp32, MI355X — round 4: force x[64] register-resident.
// N=131072 rows, D=64, K=1024. d_out = quantized[8388608] + loss[1] + indices[131072].
// Block = 256 threads / 64 rows (lane=row). Codebook streamed through LDS in
// 16 chunks of 64 codes (16 KB); wave w scans codes [w*16, w*16+16) of each chunk.
// x[64] is pinned in VGPRs via empty asm (blocks LLVM load-sinking/remat — the
// round-2/3 disease, VGPR_Count 40/52). Codebook norms read via wave-uniform
// s_load from global (no LDS copy). Distance arithmetic is shape-identical to
// the thrice-passing kernels: d = (sx + se[j]) - 2.0f*dot, sequential-FMA dot.

constexpr int Dm = 64;
constexpr int Kn = 1024;
constexpr long NR = 131072;
constexpr long QE = NR * (long)Dm;   // 8388608
constexpr int RB = 64;               // rows per block
constexpr int NBLK = (int)(NR / RB); // 2048
constexpr int CH = 64;               // codes per staged chunk (16 KB)
constexpr int NCH = Kn / CH;         // 16 chunks

__global__ __launch_bounds__(256) void vq_norms(const float* __restrict__ cb,
                                                float* __restrict__ se)
{
    int j = blockIdx.x * 256 + threadIdx.x;   // 4 blocks x 256 = 1024
    const float* e = cb + (size_t)j * Dm;
    float s = 0.f;
    #pragma unroll
    for (int d = 0; d < Dm; ++d) s = fmaf(e[d], e[d], s);  // same bits as r1-r3
    se[j] = s;
}

__global__ __launch_bounds__(256, 4) void vq_main(const float* __restrict__ inp,
                                                  const float* __restrict__ cb,
                                                  const float* __restrict__ seg,
                                                  float* __restrict__ out,
                                                  double* __restrict__ part)
{
    __shared__ float cbuf[CH * Dm];   // 16 KB staged chunk
    __shared__ float bd[4][RB];
    __shared__ int   bi[4][RB];
    __shared__ int   comb[RB];
    __shared__ double red[256];

    const int tid = threadIdx.x;
    const int w = tid >> 6;           // wave id
    const int l = tid & 63;           // lane = row-in-block

    const long row = (long)blockIdx.x * RB + l;
    const float* xr = inp + row * (long)Dm;
    float x[Dm];
    #pragma unroll
    for (int d0 = 0; d0 < Dm; d0 += 4) {
        float4 v = *reinterpret_cast<const float4*>(xr + d0);
        x[d0] = v.x; x[d0 + 1] = v.y; x[d0 + 2] = v.z; x[d0 + 3] = v.w;
    }
    float sx = 0.f;
    #pragma unroll
    for (int d = 0; d < Dm; ++d) sx = fmaf(x[d], x[d], sx);

    // Pin row + its norm in VGPRs: opaque asm kills load-sinking/rematerialization.
    #pragma unroll
    for (int d = 0; d < Dm; ++d) asm volatile("" : "+v"(x[d]));
    asm volatile("" : "+v"(sx));

    float best = __builtin_inff();
    int bidx = 0;
    const float4* gcb = reinterpret_cast<const float4*>(cb);

    for (int ch = 0; ch < NCH; ++ch) {
        __syncthreads();   // all waves done reading previous chunk
        {   // stage chunk ch: 1024 float4s, coalesced, conflict-free ds_write
            const float4* src = gcb + (size_t)ch * (CH * Dm / 4);
            float4* dst = reinterpret_cast<float4*>(cbuf);
            #pragma unroll
            for (int r = 0; r < 4; ++r) dst[r * 256 + tid] = src[r * 256 + tid];
        }
        __syncthreads();   // chunk visible to all waves

        const int jb = ch * CH + w * 16;                 // this wave's code range
        const float* ebase = cbuf + (w * 16) * Dm;
        #pragma unroll 2
        for (int c = 0; c < 16; ++c) {
            const float4* ep = reinterpret_cast<const float4*>(ebase + c * Dm);
            float a = 0.f;
            #pragma unroll
            for (int d4 = 0; d4 < 16; ++d4) {            // 16x ds_read_b128 broadcast
                float4 ev = ep[d4];
                a = fmaf(x[4 * d4 + 0], ev.x, a);
                a = fmaf(x[4 * d4 + 1], ev.y, a);
                a = fmaf(x[4 * d4 + 2], ev.z, a);
                a = fmaf(x[4 * d4 + 3], ev.w, a);
            }
            float dist = (sx + seg[jb + c]) - 2.0f * a;  // seg: uniform -> s_load
            if (dist < best) { best = dist; bidx = jb + c; }  // strict <
        }
    }

    bd[w][l] = best;
    bi[w][l] = bidx;
    __syncthreads();

    // cross-wave combine: min distance, tie -> smaller index (== first-index scan)
    if (w == 0) {
        float b = bd[0][l]; int ii = bi[0][l];
        #pragma unroll
        for (int q = 1; q < 4; ++q) {
            float d = bd[q][l]; int iq = bi[q][l];
            if (d < b || (d == b && iq < ii)) { b = d; ii = iq; }
        }
        comb[l] = ii;
        out[QE + 1 + row] = (float)ii;
    }
    __syncthreads();

    // quantized write, redistributed: thread -> (row tid>>2, dim quarter tid&3)
    const int r2 = tid >> 2;
    const int dq = (tid & 3) * 16;
    const long grow = (long)blockIdx.x * RB + r2;
    const float* xr2 = inp + grow * (long)Dm + dq;
    const float* q2  = cb + (size_t)comb[r2] * Dm + dq;
    float* outq = out + grow * (long)Dm + dq;
    double s = 0.0;
    #pragma unroll
    for (int d0 = 0; d0 < 16; d0 += 4) {
        float4 xv = *reinterpret_cast<const float4*>(xr2 + d0);
        float4 qv = *reinterpret_cast<const float4*>(q2 + d0);
        float4 ov;
        float m0 = qv.x - xv.x; ov.x = xv.x + m0;   // replicate x + (q - x)
        float m1 = qv.y - xv.y; ov.y = xv.y + m1;
        float m2 = qv.z - xv.z; ov.z = xv.z + m2;
        float m3 = qv.w - xv.w; ov.w = xv.w + m3;
        s += (double)m0 * m0 + (double)m1 * m1 + (double)m2 * m2 + (double)m3 * m3;
        *reinterpret_cast<float4*>(outq + d0) = ov;
    }

    red[tid] = s;
    __syncthreads();
    for (int k = 128; k > 0; k >>= 1) {
        if (tid < k) red[tid] += red[tid + k];
        __syncthreads();
    }
    if (tid == 0) part[blockIdx.x] = red[0];
}

__global__ __launch_bounds__(256) void vq_fin(const double* __restrict__ part,
                                              float* __restrict__ out)
{
    __shared__ double red[256];
    const int tid = threadIdx.x;
    double s = 0.0;
    #pragma unroll
    for (int k = 0; k < 8; ++k) s += part[tid + 256 * k];   // fixed order
    red[tid] = s;
    __syncthreads();
    for (int k = 128; k > 0; k >>= 1) {
        if (tid < k) red[tid] += red[tid + k];
        __syncthreads();
    }
    if (tid == 0) {
        float m = (float)(red[0] / (double)QE);   // mean((q-x)^2)
        out[QE] = m + 0.25f * m;                  // q_loss + 0.25 * e_loss
    }
}

extern "C" void kernel_launch(void* const* d_in, const int* in_sizes, int n_in,
                              void* d_out, int out_size, void* d_ws, size_t ws_size,
                              hipStream_t stream)
{
    const float* inp = (const float*)d_in[0];
    const float* cb  = (const float*)d_in[1];
    float* out = (float*)d_out;
    float* se    = (float*)d_ws;                    // 4 KB
    double* part = (double*)((char*)d_ws + 4096);   // 16 KB

    vq_norms<<<4, 256, 0, stream>>>(cb, se);
    vq_main<<<NBLK, 256, 0, stream>>>(inp, cb, se, out, part);
    vq_fin<<<1, 256, 0, stream>>>(part, out);
}

// Round 5
// 280.179 us; speedup vs baseline: 1.2128x; 1.0739x over previous
//
#include <hip/hip_runtime.h>

// VQ-VAE vector quantizer, fp32, MI355X — round 5: register-blocked GEMM tiling.
// N=131072 rows, D=64, K=1024. d_out = quantized[8388608] + loss[1] + indices[131072].
// Block = 256 threads (16x16), 64 rows x 1024 codes per block. Thread computes a
// 4x4 (row x code) distance tile; rows and codebook chunks staged in LDS with
// stride-68 padding; fragments via ds_read_b128 (<=2-way bank alias = free).
// Numerics: acc over d ascending sequential-FMA; dist = (sx+se[j]) - 2.0f*acc;
// within-thread ascending strict <, cross-thread tie -> smaller index
// == reference first-index argmin. Bit-identical to rounds 1-4 (absmax 0.0 x4).

constexpr int Dm = 64;
constexpr int Kn = 1024;
constexpr long NR = 131072;
constexpr long QE = NR * (long)Dm;   // 8388608
constexpr int RB = 64;               // rows per block
constexpr int NBLK = (int)(NR / RB); // 2048
constexpr int CH = 64;               // codes per staged chunk
constexpr int NCH = Kn / CH;         // 16
constexpr int SP4 = 17;              // padded row stride in float4s (68 floats)

__global__ __launch_bounds__(256) void vq_norms(const float* __restrict__ cb,
                                                float* __restrict__ se)
{
    int j = blockIdx.x * 256 + threadIdx.x;   // 4 blocks x 256 = 1024
    const float* e = cb + (size_t)j * Dm;
    float s = 0.f;
    #pragma unroll
    for (int d = 0; d < Dm; ++d) s = fmaf(e[d], e[d], s);  // same bits as r1-r4
    se[j] = s;
}

__global__ __launch_bounds__(256) void vq_main(const float* __restrict__ inp,
                                               const float* __restrict__ cb,
                                               const float* __restrict__ seg,
                                               float* __restrict__ out,
                                               double* __restrict__ part)
{
    __shared__ float4 xs[RB * SP4];   // 17408 B row tile
    __shared__ float4 es[CH * SP4];   // 17408 B codebook chunk
    __shared__ float  ses[Kn];        // 4 KB norms
    __shared__ float  sxs[RB];
    __shared__ float  bd[RB * 17];    // padded: 2-way max on combine reads
    __shared__ int    bi[RB * 17];
    __shared__ int    comb[RB];
    __shared__ double red[256];

    const int tid = threadIdx.x;
    const int tr = tid & 15;          // row-group id   (rows tr + 16*rr)
    const int tc = tid >> 4;          // code-group id  (codes tc + 16*cc)

    // stage row tile (coalesced) + codebook norms
    {
        const float4* src = reinterpret_cast<const float4*>(
            inp + (size_t)blockIdx.x * RB * Dm);
        #pragma unroll
        for (int r = 0; r < 4; ++r) {
            int g = r * 256 + tid;                      // 0..1023 float4s
            xs[(g >> 4) * SP4 + (g & 15)] = src[g];
        }
        #pragma unroll
        for (int k = 0; k < 4; ++k) ses[tid + 256 * k] = seg[tid + 256 * k];
    }
    __syncthreads();

    // per-row ||x||^2, sequential-FMA over d (reference op order, bits as r1-r4)
    if (tid < RB) {
        const float* xr = reinterpret_cast<const float*>(&xs[tid * SP4]);
        float s = 0.f;
        #pragma unroll
        for (int d = 0; d < Dm; ++d) s = fmaf(xr[d], xr[d], s);
        sxs[tid] = s;
    }
    __syncthreads();

    float sxr[4];
    #pragma unroll
    for (int rr = 0; rr < 4; ++rr) sxr[rr] = sxs[tr + 16 * rr];

    float best[4]; int bidx[4];
    #pragma unroll
    for (int rr = 0; rr < 4; ++rr) { best[rr] = __builtin_inff(); bidx[rr] = 0; }

    const float4* gcb = reinterpret_cast<const float4*>(cb);

    for (int ch = 0; ch < NCH; ++ch) {
        __syncthreads();   // previous chunk fully consumed
        #pragma unroll
        for (int r = 0; r < 4; ++r) {                   // stage chunk ch
            int g = r * 256 + tid;
            es[(g >> 4) * SP4 + (g & 15)] = gcb[(size_t)ch * (CH * Dm / 4) + g];
        }
        __syncthreads();

        float acc[4][4];
        #pragma unroll
        for (int rr = 0; rr < 4; ++rr)
            #pragma unroll
            for (int cc = 0; cc < 4; ++cc) acc[rr][cc] = 0.f;

        #pragma unroll 4
        for (int db = 0; db < 16; ++db) {               // d-block of 4, ascending
            float4 xf[4], ef[4];
            #pragma unroll
            for (int rr = 0; rr < 4; ++rr) xf[rr] = xs[(tr + 16 * rr) * SP4 + db];
            #pragma unroll
            for (int cc = 0; cc < 4; ++cc) ef[cc] = es[(tc + 16 * cc) * SP4 + db];
            #pragma unroll
            for (int rr = 0; rr < 4; ++rr)
                #pragma unroll
                for (int cc = 0; cc < 4; ++cc) {
                    float a = acc[rr][cc];
                    a = fmaf(xf[rr].x, ef[cc].x, a);    // d = 4*db+0 .. +3 in order
                    a = fmaf(xf[rr].y, ef[cc].y, a);
                    a = fmaf(xf[rr].z, ef[cc].z, a);
                    a = fmaf(xf[rr].w, ef[cc].w, a);
                    acc[rr][cc] = a;
                }
        }

        const int cbase = ch * CH;
        #pragma unroll
        for (int cc = 0; cc < 4; ++cc) {                // codes ascending per thread
            const int code = cbase + tc + 16 * cc;
            const float sec = ses[code];
            #pragma unroll
            for (int rr = 0; rr < 4; ++rr) {
                float dist = (sxr[rr] + sec) - 2.0f * acc[rr][cc];  // r1-r4 formula
                if (dist < best[rr]) { best[rr] = dist; bidx[rr] = code; }
            }
        }
    }

    #pragma unroll
    for (int rr = 0; rr < 4; ++rr) {
        int row = tr + 16 * rr;
        bd[row * 17 + tc] = best[rr];
        bi[row * 17 + tc] = bidx[rr];
    }
    __syncthreads();

    // combine 16 code-subsets per row: min dist, tie -> smaller index
    if (tid < RB) {
        float b = bd[tid * 17]; int ii = bi[tid * 17];
        #pragma unroll
        for (int q = 1; q < 16; ++q) {
            float d = bd[tid * 17 + q]; int iq = bi[tid * 17 + q];
            if (d < b || (d == b && iq < ii)) { b = d; ii = iq; }
        }
        comb[tid] = ii;
        out[QE + 1 + (long)blockIdx.x * RB + tid] = (float)ii;
    }
    __syncthreads();

    // quantized write (verbatim round-4 epilogue): thread -> (row tid>>2, quarter tid&3)
    const int r2 = tid >> 2;
    const int dq = (tid & 3) * 16;
    const long grow = (long)blockIdx.x * RB + r2;
    const float* xr2 = inp + grow * (long)Dm + dq;
    const float* q2  = cb + (size_t)comb[r2] * Dm + dq;
    float* outq = out + grow * (long)Dm + dq;
    double s = 0.0;
    #pragma unroll
    for (int d0 = 0; d0 < 16; d0 += 4) {
        float4 xv = *reinterpret_cast<const float4*>(xr2 + d0);
        float4 qv = *reinterpret_cast<const float4*>(q2 + d0);
        float4 ov;
        float m0 = qv.x - xv.x; ov.x = xv.x + m0;   // replicate x + (q - x)
        float m1 = qv.y - xv.y; ov.y = xv.y + m1;
        float m2 = qv.z - xv.z; ov.z = xv.z + m2;
        float m3 = qv.w - xv.w; ov.w = xv.w + m3;
        s += (double)m0 * m0 + (double)m1 * m1 + (double)m2 * m2 + (double)m3 * m3;
        *reinterpret_cast<float4*>(outq + d0) = ov;
    }

    red[tid] = s;
    __syncthreads();
    for (int k = 128; k > 0; k >>= 1) {
        if (tid < k) red[tid] += red[tid + k];
        __syncthreads();
    }
    if (tid == 0) part[blockIdx.x] = red[0];
}

__global__ __launch_bounds__(256) void vq_fin(const double* __restrict__ part,
                                              float* __restrict__ out)
{
    __shared__ double red[256];
    const int tid = threadIdx.x;
    double s = 0.0;
    #pragma unroll
    for (int k = 0; k < 8; ++k) s += part[tid + 256 * k];   // fixed order
    red[tid] = s;
    __syncthreads();
    for (int k = 128; k > 0; k >>= 1) {
        if (tid < k) red[tid] += red[tid + k];
        __syncthreads();
    }
    if (tid == 0) {
        float m = (float)(red[0] / (double)QE);   // mean((q-x)^2)
        out[QE] = m + 0.25f * m;                  // q_loss + 0.25 * e_loss
    }
}

extern "C" void kernel_launch(void* const* d_in, const int* in_sizes, int n_in,
                              void* d_out, int out_size, void* d_ws, size_t ws_size,
                              hipStream_t stream)
{
    const float* inp = (const float*)d_in[0];
    const float* cb  = (const float*)d_in[1];
    float* out = (float*)d_out;
    float* se    = (float*)d_ws;                    // 4 KB
    double* part = (double*)((char*)d_ws + 4096);   // 16 KB

    vq_norms<<<4, 256, 0, stream>>>(cb, se);
    vq_main<<<NBLK, 256, 0, stream>>>(inp, cb, se, out, part);
    vq_fin<<<1, 256, 0, stream>>>(part, out);
}